// Round 1
// baseline (1763.619 us; speedup 1.0000x reference)
//
#include <hip/hip_runtime.h>
#include <stdint.h>

typedef short bf16x8 __attribute__((ext_vector_type(8)));
typedef float f32x4 __attribute__((ext_vector_type(4)));

#define N_IMG 128
#define C_IN 512
#define NP1 25
#define C1 537
#define C1P 544
#define HID 256
#define RR 28
#define PLANE 784               // 28*28
#define P_TOTAL (N_IMG * PLANE) // 100352

__constant__ int c_dh[9] = {-1, -1, -1, 0, 0, -2, 0, 2, 3};
__constant__ int c_dw[9] = {-3, -1, 1, 0, 2, 1, -1, 0, 1};

// zero-initialized device BSS, never written -> stays zero across calls.
// OOB tap reads are redirected here. Max offset read: 544*2B + 16B < 4KB.
__device__ __align__(16) uint16_t g_zeropage[2048];

__device__ __forceinline__ uint16_t f2bf(float f) {
  union { float f; uint32_t u; } v; v.f = f;
  return (uint16_t)((v.u + 0x7fffu + ((v.u >> 16) & 1u)) >> 16);
}

__device__ __forceinline__ void load16(void* lds, const void* g) {
  __builtin_amdgcn_global_load_lds(
      (__attribute__((address_space(1))) void*)(g),
      (__attribute__((address_space(3))) void*)(lds), 16, 0, 0);
}

// ---------------- max-pool 4x4: fine_segm [128,25,112,112] -> pooled NCHW [128,25,28,28]
__global__ void pool_kernel(const float* __restrict__ fs, float* __restrict__ pooled) {
  int u = blockIdx.x * 256 + threadIdx.x;
  if (u >= N_IMG * NP1 * PLANE) return;
  int w = u % RR;
  int tmp = u / RR;
  int h = tmp % RR; tmp /= RR;
  int c = tmp % NP1;
  int n = tmp / NP1;
  const float* base = fs + (((size_t)(n * NP1 + c)) * 112 + h * 4) * 112 + w * 4;
  float m = -INFINITY;
#pragma unroll
  for (int i = 0; i < 4; i++) {
    float4 v = *(const float4*)(base + (size_t)i * 112);
    m = fmaxf(m, fmaxf(fmaxf(v.x, v.y), fmaxf(v.z, v.w)));
  }
  pooled[u] = m;
}

// ---------------- build X0: NCHW fp32 (features | pooled | zero-pad) -> NHWC bf16 [100352][544]
__global__ void build_x0(const float* __restrict__ feat, const float* __restrict__ pooled,
                         uint16_t* __restrict__ X0) {
  __shared__ float tile[32][33];
  int n = blockIdx.z;
  int c0 = blockIdx.y * 32;
  int p0 = blockIdx.x * 32;
  int tx = threadIdx.x & 31;
  int ty = threadIdx.x >> 5; // 0..7
  int p = p0 + tx;
#pragma unroll
  for (int k = 0; k < 4; k++) {
    int cl = ty + k * 8;
    int c = c0 + cl;
    float v = 0.f;
    if (p < PLANE) {
      if (c < C_IN)
        v = feat[((size_t)(n * C_IN + c)) * PLANE + p];
      else if (c < C1)
        v = pooled[((size_t)(n * NP1 + (c - C_IN))) * PLANE + p];
    }
    tile[cl][tx] = v;
  }
  __syncthreads();
#pragma unroll
  for (int k = 0; k < 4; k++) {
    int pl = ty + k * 8;
    int pp = p0 + pl;
    if (pp < PLANE) {
      int c = c0 + tx;
      X0[((size_t)n * PLANE + pp) * C1P + c] = f2bf(tile[tx][pl]);
    }
  }
}

// ---------------- weights fp32 [O,C,3,3] -> bf16 [9][256][CPAD] (c-contiguous, zero-padded)
__global__ void wconv_kernel(const float* __restrict__ w, uint16_t* __restrict__ wbf,
                             int C, int CPAD) {
  int v = blockIdx.x * 256 + threadIdx.x;
  if (v >= 9 * HID * CPAD) return;
  int c = v % CPAD;
  int tmp = v / CPAD;
  int o = tmp % HID;
  int t = tmp / HID;
  uint16_t out = 0;
  if (c < C) out = f2bf(w[((size_t)(o * C + c)) * 9 + t]);
  wbf[v] = out;
}

// ---------------- implicit-GEMM conv layer: X NHWC bf16 -> Y (bf16 NHWC) or final fp32 NCHW
// tile: 128 positions x 128 out-channels, K = 9 taps x CPAD channels, BK=32
template <int CPAD, bool FINAL>
__global__ __launch_bounds__(256) void conv_mfma(const uint16_t* __restrict__ Xin,
                                                 const uint16_t* __restrict__ Wt,
                                                 uint16_t* __restrict__ Yout,
                                                 float* __restrict__ Fout) {
  // chunk-major LDS: [chunk(4)][pos/o (128)][8 bf16] -> conflict-free ds_read_b128
  __shared__ __align__(16) uint16_t Albs[4 * 128 * 8];
  __shared__ __align__(16) uint16_t Blds[4 * 128 * 8];

  const int tid = threadIdx.x;
  const int lane = tid & 63;
  const int wv = tid >> 6; // wave id 0..3, also its staging chunk
  const int wr = wv >> 1;  // position half
  const int wc = wv & 1;   // out-channel half
  const int p0 = blockIdx.x * 128;
  const int ob = blockIdx.y * 128;

  // this lane's two staging positions (halves 0 and 1)
  const int pA = p0 + lane;
  const int pB = p0 + 64 + lane;
  const int nA = pA / PLANE, rAq = pA % PLANE, hA = rAq / RR, wA = rAq % RR;
  const int nB = pB / PLANE, rBq = pB % PLANE, hB = rBq / RR, wB = rBq % RR;

  const uint16_t* wrow0 = Wt + (size_t)(ob + lane) * CPAD;
  const uint16_t* wrow1 = Wt + (size_t)(ob + 64 + lane) * CPAD;

  f32x4 acc[4][4];
#pragma unroll
  for (int i = 0; i < 4; i++)
#pragma unroll
    for (int j = 0; j < 4; j++) acc[i][j] = (f32x4){0.f, 0.f, 0.f, 0.f};

  const int q = lane >> 4, l15 = lane & 15;

  for (int t = 0; t < 9; t++) {
    const int dh = c_dh[t], dw = c_dw[t];
    const int hsA = hA + dh, wsA = wA + dw;
    const int hsB = hB + dh, wsB = wB + dw;
    const bool vA = (hsA >= 0) & (hsA < RR) & (wsA >= 0) & (wsA < RR);
    const bool vB = (hsB >= 0) & (hsB < RR) & (wsB >= 0) & (wsB < RR);
    const uint16_t* sA =
        vA ? (Xin + (size_t)(nA * PLANE + hsA * RR + wsA) * CPAD) : g_zeropage;
    const uint16_t* sB =
        vB ? (Xin + (size_t)(nB * PLANE + hsB * RR + wsB) * CPAD) : g_zeropage;
    const uint16_t* wt0 = wrow0 + (size_t)t * HID * CPAD;
    const uint16_t* wt1 = wrow1 + (size_t)t * HID * CPAD;

    for (int kc = 0; kc < CPAD / 32; kc++) {
      const int c0 = kc * 32 + wv * 8; // this wave stages chunk wv
      load16(&Albs[(wv * 128) * 8], sA + c0);
      load16(&Albs[(wv * 128 + 64) * 8], sB + c0);
      load16(&Blds[(wv * 128) * 8], wt0 + c0);
      load16(&Blds[(wv * 128 + 64) * 8], wt1 + c0);
      __syncthreads();

      bf16x8 af[4], bfr[4];
#pragma unroll
      for (int i = 0; i < 4; i++)
        af[i] = *(const bf16x8*)&Albs[(q * 128 + wr * 64 + i * 16 + l15) * 8];
#pragma unroll
      for (int j = 0; j < 4; j++)
        bfr[j] = *(const bf16x8*)&Blds[(q * 128 + wc * 64 + j * 16 + l15) * 8];

#pragma unroll
      for (int i = 0; i < 4; i++)
#pragma unroll
        for (int j = 0; j < 4; j++)
          acc[i][j] =
              __builtin_amdgcn_mfma_f32_16x16x32_bf16(af[i], bfr[j], acc[i][j], 0, 0, 0);
      __syncthreads();
    }
  }

  // epilogue: C/D mapping col=lane&15 (o), row=(lane>>4)*4+reg (position)
  if (!FINAL) {
#pragma unroll
    for (int i = 0; i < 4; i++) {
#pragma unroll
      for (int r = 0; r < 4; r++) {
        const int ppos = p0 + wr * 64 + i * 16 + q * 4 + r;
        uint16_t* row = Yout + (size_t)ppos * HID + (ob + wc * 64 + l15);
#pragma unroll
        for (int j = 0; j < 4; j++) row[j * 16] = f2bf(fmaxf(acc[i][j][r], 0.f));
      }
    }
  } else {
#pragma unroll
    for (int i = 0; i < 4; i++) {
      const int ppos = p0 + wr * 64 + i * 16 + q * 4; // multiple of 4
      const int n = ppos / PLANE, rem = ppos % PLANE; // rem % 4 == 0, no row-cross
#pragma unroll
      for (int j = 0; j < 4; j++) {
        const int o = ob + wc * 64 + j * 16 + l15;
        f32x4 v = acc[i][j];
        v[0] = fmaxf(v[0], 0.f);
        v[1] = fmaxf(v[1], 0.f);
        v[2] = fmaxf(v[2], 0.f);
        v[3] = fmaxf(v[3], 0.f);
        *(f32x4*)(Fout + ((size_t)(n * HID + o)) * PLANE + rem) = v;
      }
    }
  }
}

extern "C" void kernel_launch(void* const* d_in, const int* in_sizes, int n_in,
                              void* d_out, int out_size, void* d_ws, size_t ws_size,
                              hipStream_t stream) {
  const float* feat = (const float*)d_in[0];
  const float* fseg = (const float*)d_in[1];
  const float* w1 = (const float*)d_in[2];
  const float* w2 = (const float*)d_in[3];
  const float* w3 = (const float*)d_in[4];
  const float* w4 = (const float*)d_in[5];
  float* out = (float*)d_out;

  uint8_t* p = (uint8_t*)d_ws;
  uint16_t* X0 = (uint16_t*)p; p += (size_t)P_TOTAL * C1P * 2;   // 109.2 MB
  uint16_t* XA = (uint16_t*)p; p += (size_t)P_TOTAL * HID * 2;   // 51.4 MB
  uint16_t* XB = (uint16_t*)p; p += (size_t)P_TOTAL * HID * 2;   // 51.4 MB
  float* pooled = (float*)p;   p += (size_t)N_IMG * NP1 * PLANE * 4; // 10.0 MB
  uint16_t* W1b = (uint16_t*)p; p += (size_t)9 * HID * C1P * 2;  // 2.5 MB
  uint16_t* W2b = (uint16_t*)p; p += (size_t)9 * HID * HID * 2;  // 1.18 MB
  uint16_t* W3b = (uint16_t*)p; p += (size_t)9 * HID * HID * 2;
  uint16_t* W4b = (uint16_t*)p; p += (size_t)9 * HID * HID * 2;

  // front-end
  pool_kernel<<<(N_IMG * NP1 * PLANE + 255) / 256, 256, 0, stream>>>(fseg, pooled);
  wconv_kernel<<<(9 * HID * C1P + 255) / 256, 256, 0, stream>>>(w1, W1b, C1, C1P);
  wconv_kernel<<<(9 * HID * HID + 255) / 256, 256, 0, stream>>>(w2, W2b, HID, HID);
  wconv_kernel<<<(9 * HID * HID + 255) / 256, 256, 0, stream>>>(w3, W3b, HID, HID);
  wconv_kernel<<<(9 * HID * HID + 255) / 256, 256, 0, stream>>>(w4, W4b, HID, HID);
  build_x0<<<dim3(25, 17, N_IMG), 256, 0, stream>>>(feat, pooled, X0);

  // 4 deform-conv layers
  dim3 cgrid(P_TOTAL / 128, 2);
  conv_mfma<C1P, false><<<cgrid, 256, 0, stream>>>(X0, W1b, XA, nullptr);
  conv_mfma<HID, false><<<cgrid, 256, 0, stream>>>(XA, W2b, XB, nullptr);
  conv_mfma<HID, false><<<cgrid, 256, 0, stream>>>(XB, W3b, XA, nullptr);
  conv_mfma<HID, true><<<cgrid, 256, 0, stream>>>(XA, W4b, nullptr, out);
}

// Round 2
// 1276.342 us; speedup vs baseline: 1.3818x; 1.3818x over previous
//
#include <hip/hip_runtime.h>
#include <stdint.h>

typedef short bf16x8 __attribute__((ext_vector_type(8)));
typedef float f32x4 __attribute__((ext_vector_type(4)));

#define N_IMG 128
#define C_IN 512
#define NP1 25
#define C1 537
#define C1P 576               // padded to 9*64 for BK=64
#define HID 256
#define RR 28
#define PLANE 784               // 28*28
#define P_TOTAL (N_IMG * PLANE) // 100352

__constant__ int c_dh[9] = {-1, -1, -1, 0, 0, -2, 0, 2, 3};
__constant__ int c_dw[9] = {-3, -1, 1, 0, 2, 1, -1, 0, 1};

// zero-initialized device BSS, never written -> stays zero across calls.
// OOB tap reads are redirected here. Max offset read: 576*2B < 4KB.
__device__ __align__(16) uint16_t g_zeropage[2048];

__device__ __forceinline__ uint16_t f2bf(float f) {
  union { float f; uint32_t u; } v; v.f = f;
  return (uint16_t)((v.u + 0x7fffu + ((v.u >> 16) & 1u)) >> 16);
}

__device__ __forceinline__ void load16(void* lds, const void* g) {
  __builtin_amdgcn_global_load_lds(
      (__attribute__((address_space(1))) void*)(g),
      (__attribute__((address_space(3))) void*)(lds), 16, 0, 0);
}

// ---------------- max-pool 4x4: fine_segm [128,25,112,112] -> pooled NCHW [128,25,28,28]
__global__ void pool_kernel(const float* __restrict__ fs, float* __restrict__ pooled) {
  int u = blockIdx.x * 256 + threadIdx.x;
  if (u >= N_IMG * NP1 * PLANE) return;
  int w = u % RR;
  int tmp = u / RR;
  int h = tmp % RR; tmp /= RR;
  int c = tmp % NP1;
  int n = tmp / NP1;
  const float* base = fs + (((size_t)(n * NP1 + c)) * 112 + h * 4) * 112 + w * 4;
  float m = -INFINITY;
#pragma unroll
  for (int i = 0; i < 4; i++) {
    float4 v = *(const float4*)(base + (size_t)i * 112);
    m = fmaxf(m, fmaxf(fmaxf(v.x, v.y), fmaxf(v.z, v.w)));
  }
  pooled[u] = m;
}

// ---------------- build X0: NCHW fp32 (features | pooled | zero-pad) -> NHWC bf16 [100352][576]
// 64 pos x 64 ch tile; vectorized 16B stores.
__global__ void build_x0(const float* __restrict__ feat, const float* __restrict__ pooled,
                         uint16_t* __restrict__ X0) {
  __shared__ float tile[64][65];
  const int n = blockIdx.z;
  const int c0 = blockIdx.y * 64;
  const int p0 = blockIdx.x * 64;
  const int tx = threadIdx.x & 63;  // pos
  const int ty = threadIdx.x >> 6;  // 0..3
  const int p = p0 + tx;
#pragma unroll
  for (int k = 0; k < 16; k++) {
    const int cl = ty + k * 4;
    const int c = c0 + cl;
    float v = 0.f;
    if (p < PLANE) {
      if (c < C_IN)
        v = feat[((size_t)(n * C_IN + c)) * PLANE + p];
      else if (c < C1)
        v = pooled[((size_t)(n * NP1 + (c - C_IN))) * PLANE + p];
    }
    tile[cl][tx] = v;
  }
  __syncthreads();
#pragma unroll
  for (int k = 0; k < 2; k++) {
    const int u = threadIdx.x + k * 256; // 0..511
    const int pl = u >> 3;               // 0..63
    const int ch = u & 7;                // 16B chunk (8 channels)
    if (p0 + pl < PLANE) {
      bf16x8 v;
#pragma unroll
      for (int e = 0; e < 8; e++) v[e] = (short)f2bf(tile[ch * 8 + e][pl]);
      *(bf16x8*)&X0[((size_t)n * PLANE + p0 + pl) * C1P + c0 + ch * 8] = v;
    }
  }
}

// ---------------- weights fp32 [O,C,3,3] -> bf16 [9][256][CPAD] (c-contiguous, zero-padded)
__global__ void wconv_kernel(const float* __restrict__ w, uint16_t* __restrict__ wbf,
                             int C, int CPAD) {
  int v = blockIdx.x * 256 + threadIdx.x;
  if (v >= 9 * HID * CPAD) return;
  int c = v % CPAD;
  int tmp = v / CPAD;
  int o = tmp % HID;
  int t = tmp / HID;
  uint16_t out = 0;
  if (c < C) out = f2bf(w[((size_t)(o * C + c)) * 9 + t]);
  wbf[v] = out;
}

// ---------------- implicit-GEMM conv layer, BK=64, coalesced swizzled staging.
// LDS tile [128 rows][64 K] bf16, 128B rows; 16B slot s of row r holds global
// K-granule g = s ^ (r&7) (XOR swizzle: rows alias all 32 banks otherwise).
// tile: 128 positions x 128 out-channels, K = 9 taps x CPAD
template <int CPAD, bool FINAL>
__global__ __launch_bounds__(256) void conv_mfma(const uint16_t* __restrict__ Xin,
                                                 const uint16_t* __restrict__ Wt,
                                                 uint16_t* __restrict__ Yout,
                                                 float* __restrict__ Fout) {
  __shared__ __align__(16) uint16_t Albs[128 * 64];
  __shared__ __align__(16) uint16_t Blds[128 * 64];

  const int tid = threadIdx.x;
  const int lane = tid & 63;
  const int wv = tid >> 6; // wave id 0..3
  const int wr = wv >> 1;  // position half (compute)
  const int wc = wv & 1;   // out-channel half (compute)
  const int p0 = blockIdx.x * 128;
  const int ob = blockIdx.y * 128;

  // staging lane mapping: 8 rows x 8 slots per instruction
  const int lr = lane >> 3; // row-within-8
  const int ls = lane & 7;  // 16B slot
  const int g16 = (ls ^ lr) * 16; // swizzled global granule byte offset

  // my 4 staged A rows: p-local = wv*32 + j*8 + lr
  int an[4], ah[4], aw[4];
#pragma unroll
  for (int j = 0; j < 4; j++) {
    const int pp = p0 + wv * 32 + j * 8 + lr;
    an[j] = pp / PLANE;
    const int r = pp % PLANE;
    ah[j] = r / RR;
    aw[j] = r % RR;
  }
  // B: row o = ob + wv*32 + lr (+ j*8 via stride)
  const char* Bbase =
      (const char*)Wt + ((size_t)(ob + wv * 32 + lr) * CPAD) * 2 + g16;
  char* AldsW = (char*)Albs + wv * 4096;
  char* BldsW = (char*)Blds + wv * 4096;

  f32x4 acc[4][4];
#pragma unroll
  for (int i = 0; i < 4; i++)
#pragma unroll
    for (int j = 0; j < 4; j++) acc[i][j] = (f32x4){0.f, 0.f, 0.f, 0.f};

  const int q = lane >> 4, l15 = lane & 15;
  const int sxor = l15 & 7; // row&7 for fragment reads

  for (int t = 0; t < 9; t++) {
    const int dh = c_dh[t], dw = c_dw[t];
    const char* Aptr[4];
#pragma unroll
    for (int j = 0; j < 4; j++) {
      const int hs = ah[j] + dh, ws = aw[j] + dw;
      const bool v = (hs >= 0) & (hs < RR) & (ws >= 0) & (ws < RR);
      Aptr[j] = v ? (const char*)(Xin + (size_t)(an[j] * PLANE + hs * RR + ws) * CPAD) + g16
                  : (const char*)g_zeropage;
    }
    const char* Bt = Bbase + (size_t)t * HID * CPAD * 2;

    for (int kc = 0; kc < CPAD / 64; kc++) {
      const int ko = kc * 128;
#pragma unroll
      for (int j = 0; j < 4; j++) load16(AldsW + j * 1024, Aptr[j] + ko);
#pragma unroll
      for (int j = 0; j < 4; j++)
        load16(BldsW + j * 1024, Bt + (size_t)j * (8 * CPAD * 2) + ko);
      __syncthreads();

#pragma unroll
      for (int kh = 0; kh < 2; kh++) {
        bf16x8 af[4], bfr[4];
        const int s8 = ((kh * 4 + q) ^ sxor) * 8;
#pragma unroll
        for (int i = 0; i < 4; i++)
          af[i] = *(const bf16x8*)&Albs[(wr * 64 + i * 16 + l15) * 64 + s8];
#pragma unroll
        for (int j = 0; j < 4; j++)
          bfr[j] = *(const bf16x8*)&Blds[(wc * 64 + j * 16 + l15) * 64 + s8];
#pragma unroll
        for (int i = 0; i < 4; i++)
#pragma unroll
          for (int j = 0; j < 4; j++)
            acc[i][j] =
                __builtin_amdgcn_mfma_f32_16x16x32_bf16(af[i], bfr[j], acc[i][j], 0, 0, 0);
      }
      __syncthreads();
    }
  }

  // epilogue: C/D mapping col=lane&15 (o), row=(lane>>4)*4+reg (position)
  if (!FINAL) {
#pragma unroll
    for (int i = 0; i < 4; i++) {
#pragma unroll
      for (int r = 0; r < 4; r++) {
        const int ppos = p0 + wr * 64 + i * 16 + q * 4 + r;
        uint16_t* row = Yout + (size_t)ppos * HID + (ob + wc * 64 + l15);
#pragma unroll
        for (int j = 0; j < 4; j++) row[j * 16] = f2bf(fmaxf(acc[i][j][r], 0.f));
      }
    }
  } else {
#pragma unroll
    for (int i = 0; i < 4; i++) {
      const int ppos = p0 + wr * 64 + i * 16 + q * 4; // multiple of 4
      const int n = ppos / PLANE, rem = ppos % PLANE; // rem % 4 == 0, no row-cross
#pragma unroll
      for (int j = 0; j < 4; j++) {
        const int o = ob + wc * 64 + j * 16 + l15;
        f32x4 v = acc[i][j];
        v[0] = fmaxf(v[0], 0.f);
        v[1] = fmaxf(v[1], 0.f);
        v[2] = fmaxf(v[2], 0.f);
        v[3] = fmaxf(v[3], 0.f);
        *(f32x4*)(Fout + ((size_t)(n * HID + o)) * PLANE + rem) = v;
      }
    }
  }
}

extern "C" void kernel_launch(void* const* d_in, const int* in_sizes, int n_in,
                              void* d_out, int out_size, void* d_ws, size_t ws_size,
                              hipStream_t stream) {
  const float* feat = (const float*)d_in[0];
  const float* fseg = (const float*)d_in[1];
  const float* w1 = (const float*)d_in[2];
  const float* w2 = (const float*)d_in[3];
  const float* w3 = (const float*)d_in[4];
  const float* w4 = (const float*)d_in[5];
  float* out = (float*)d_out;

  uint8_t* p = (uint8_t*)d_ws;
  uint16_t* X0 = (uint16_t*)p; p += (size_t)P_TOTAL * C1P * 2;   // 115.6 MB
  uint16_t* XA = (uint16_t*)p; p += (size_t)P_TOTAL * HID * 2;   // 51.4 MB
  uint16_t* XB = (uint16_t*)p; p += (size_t)P_TOTAL * HID * 2;   // 51.4 MB
  float* pooled = (float*)p;   p += (size_t)N_IMG * NP1 * PLANE * 4; // 10.0 MB
  uint16_t* W1b = (uint16_t*)p; p += (size_t)9 * HID * C1P * 2;  // 2.65 MB
  uint16_t* W2b = (uint16_t*)p; p += (size_t)9 * HID * HID * 2;  // 1.18 MB
  uint16_t* W3b = (uint16_t*)p; p += (size_t)9 * HID * HID * 2;
  uint16_t* W4b = (uint16_t*)p; p += (size_t)9 * HID * HID * 2;

  // front-end
  pool_kernel<<<(N_IMG * NP1 * PLANE + 255) / 256, 256, 0, stream>>>(fseg, pooled);
  wconv_kernel<<<(9 * HID * C1P + 255) / 256, 256, 0, stream>>>(w1, W1b, C1, C1P);
  wconv_kernel<<<(9 * HID * HID + 255) / 256, 256, 0, stream>>>(w2, W2b, HID, HID);
  wconv_kernel<<<(9 * HID * HID + 255) / 256, 256, 0, stream>>>(w3, W3b, HID, HID);
  wconv_kernel<<<(9 * HID * HID + 255) / 256, 256, 0, stream>>>(w4, W4b, HID, HID);
  build_x0<<<dim3(13, 9, N_IMG), 256, 0, stream>>>(feat, pooled, X0);

  // 4 deform-conv layers
  dim3 cgrid(P_TOTAL / 128, 2);
  conv_mfma<C1P, false><<<cgrid, 256, 0, stream>>>(X0, W1b, XA, nullptr);
  conv_mfma<HID, false><<<cgrid, 256, 0, stream>>>(XA, W2b, XB, nullptr);
  conv_mfma<HID, false><<<cgrid, 256, 0, stream>>>(XB, W3b, XA, nullptr);
  conv_mfma<HID, true><<<cgrid, 256, 0, stream>>>(XA, W4b, nullptr, out);
}